// Round 3
// baseline (2052.610 us; speedup 1.0000x reference)
//
#include <hip/hip_runtime.h>

// Chamfer distance, B=16, N=M=4096, D=3.
// dist(i,j) = n1 + n2 - 2*x1.x2 as ONE bf16 MFMA per 32x32 tile (norms folded
// into padded K slots, hi/lo bf16 split => exact-grade).
// R7 (spill fix, take 2): R5/R6 spilled identically (VGPR=84, 845 MB scratch
// writes) because the pre-RA scheduler clusters MFMAs across source scopes,
// recreating a 4+-live f32x16 set. Fixes:
//  - sched_barrier(0) after each accumulator pair is folded -> hard 2-live cap
//  - g-loop fully unrolled via macros, explicit bufA/bufB double buffer,
//    every register-array index a literal (no runtime-index scratch demotion)
//  - launch_bounds (256,2): VGPR cap 256, spill impossible for ~140-reg live
// Fusion (one pass per batch, half the MFMAs of the two-pass R4):
//  - row-min: rm0/rm1 register fold (v_min3), direct store to rowpart
//  - col-min: per-tile min3 tree -> shfl_xor(32) -> per-wave LDS -> block
//    merge -> colpart; reduce kernel does cross-rg/cq mins

typedef __attribute__((ext_vector_type(8))) __bf16 bf16x8;
typedef __attribute__((ext_vector_type(16))) float f32x16;

#define PTS 4096
#define TILES 128  // PTS/32
#define NB 16

__device__ __forceinline__ unsigned f2bf(float f) {
  unsigned u = __float_as_uint(f);
  return (u + 0x7FFFu + ((u >> 16) & 1u)) >> 16;  // RNE bf16 bits
}
__device__ __forceinline__ float bf2f(unsigned s) {
  return __uint_as_float(s << 16);
}
__device__ __forceinline__ unsigned pk(unsigned lo, unsigned hi) {
  return (lo & 0xFFFFu) | (hi << 16);
}
// min over the 16 elements of one accumulator: 7x v_min3 + v_min
__device__ __forceinline__ float tree16(const f32x16 a) {
  const float u0 = fminf(fminf(a[0], a[1]), a[2]);
  const float u1 = fminf(fminf(a[3], a[4]), a[5]);
  const float u2 = fminf(fminf(a[6], a[7]), a[8]);
  const float u3 = fminf(fminf(a[9], a[10]), a[11]);
  const float u4 = fminf(fminf(a[12], a[13]), a[14]);
  const float v0 = fminf(fminf(u0, u1), a[15]);
  const float v1 = fminf(fminf(u2, u3), u4);
  return fminf(v0, v1);
}

// ---- prepack x2-side (column) fragments + zero out ----
// Bfr[((b*TILES+t)*2+h)*32 + l31]
// B k-vec: w0=[Hx Hy Hz Lx Ly Lz Hx Hy]  w1=[Hz nh nl 1 1 0 0 0], H,L split -2q.
__global__ __launch_bounds__(256) void prepack_b(const float* __restrict__ x2,
                                                 uint4* __restrict__ Bfr,
                                                 float* __restrict__ out) {
  const int id = blockIdx.x * 256 + threadIdx.x;  // NB*PTS = 65536
  if (id < NB) out[id] = 0.f;                     // reduce uses atomicAdd
  const int b = id >> 12;
  const int j = id & (PTS - 1);
  const float* q = x2 + (size_t)(b * PTS + j) * 3;
  const float x = q[0], y = q[1], z = q[2];
  const float sx = -2.f * x, sy = -2.f * y, sz = -2.f * z;
  const unsigned Hx = f2bf(sx), Hy = f2bf(sy), Hz = f2bf(sz);
  const unsigned Lx = f2bf(sx - bf2f(Hx));
  const unsigned Ly = f2bf(sy - bf2f(Hy));
  const unsigned Lz = f2bf(sz - bf2f(Hz));
  const float n = fmaf(x, x, fmaf(y, y, z * z));
  const unsigned nh = f2bf(n), nl = f2bf(n - bf2f(nh));
  const unsigned one = 0x3F80u;
  uint4 w0, w1;
  w0.x = pk(Hx, Hy); w0.y = pk(Hz, Lx); w0.z = pk(Ly, Lz); w0.w = pk(Hx, Hy);
  w1.x = pk(Hz, nh); w1.y = pk(nl, one); w1.z = pk(one, 0u); w1.w = 0u;
  uint4* base = Bfr + ((size_t)(b * TILES + (j >> 5)) * 2) * 32 + (j & 31);
  base[0]  = w0;   // half 0 (k 0..7)
  base[32] = w1;   // half 1 (k 8..15)
}

// One tile-pair: 2 col-tiles x 2 row-frags. Strict 2-live accumulators,
// enforced by sched_barrier(0) fences.
#define TSTEP(G, CUR, TS)                                                     \
  do {                                                                        \
    const bf16x8 b0 = CUR[2 * (TS)], b1 = CUR[2 * (TS) + 1];                  \
    float cp0, cp1;                                                           \
    {                                                                         \
      const f32x16 a0 =                                                       \
          __builtin_amdgcn_mfma_f32_32x32x16_bf16(af0, b0, zero, 0, 0, 0);    \
      const f32x16 a1 =                                                       \
          __builtin_amdgcn_mfma_f32_32x32x16_bf16(af0, b1, zero, 0, 0, 0);    \
      _Pragma("unroll") for (int e = 0; e < 16; ++e)                          \
          rm0[e] = fminf(fminf(a0[e], a1[e]), rm0[e]);                        \
      cp0 = tree16(a0);                                                       \
      cp1 = tree16(a1);                                                       \
    }                                                                         \
    __builtin_amdgcn_sched_barrier(0);                                        \
    float c0, c1;                                                             \
    {                                                                         \
      const f32x16 a0 =                                                       \
          __builtin_amdgcn_mfma_f32_32x32x16_bf16(af1, b0, zero, 0, 0, 0);    \
      const f32x16 a1 =                                                       \
          __builtin_amdgcn_mfma_f32_32x32x16_bf16(af1, b1, zero, 0, 0, 0);    \
      _Pragma("unroll") for (int e = 0; e < 16; ++e)                          \
          rm1[e] = fminf(fminf(a0[e], a1[e]), rm1[e]);                        \
      c0 = fminf(cp0, tree16(a0));                                            \
      c1 = fminf(cp1, tree16(a1));                                            \
    }                                                                         \
    c0 = fminf(c0, __shfl_xor(c0, 32));                                       \
    c1 = fminf(c1, __shfl_xor(c1, 32));                                       \
    if (half == 0) {                                                          \
      colw[wave][((G) * 4 + 2 * (TS)) * 32 + l31] = c0;                       \
      colw[wave][((G) * 4 + 2 * (TS) + 1) * 32 + l31] = c1;                   \
    }                                                                         \
    __builtin_amdgcn_sched_barrier(0);                                        \
  } while (0)

// One group: prefetch the next 4 tiles into NXT while computing CUR's 4.
#define GBODY(G, CUR, NXT)                                                    \
  do {                                                                        \
    NXT[0] = *(const bf16x8*)&bp[((((G) + 1) & 7) * 4 + 0) * 64 + off];       \
    NXT[1] = *(const bf16x8*)&bp[((((G) + 1) & 7) * 4 + 1) * 64 + off];       \
    NXT[2] = *(const bf16x8*)&bp[((((G) + 1) & 7) * 4 + 2) * 64 + off];       \
    NXT[3] = *(const bf16x8*)&bp[((((G) + 1) & 7) * 4 + 3) * 64 + off];       \
    TSTEP(G, CUR, 0);                                                         \
    TSTEP(G, CUR, 1);                                                         \
  } while (0)

// ---- main: 256 threads (4 waves) share one 32-tile col stream (L2 reuse).
// grid.x = 64 slices (b,cq) -> XCD = x%8 pins slice stream to one L2.
// grid.y = 16 row-groups of 256 rows.  One pass: row-min AND col-min.
__global__ __launch_bounds__(256, 2) void chamfer_main(
    const float* __restrict__ x1, const uint4* __restrict__ Bfr,
    float* __restrict__ rowpart, float* __restrict__ colpart) {
  const int s  = blockIdx.x;           // (b, col-quarter)
  const int b  = s >> 2;
  const int cq = s & 3;
  const int rg = blockIdx.y;           // row-group: 8 row-tiles

  const int tid  = threadIdx.x;
  const int lane = tid & 63;
  const int half = lane >> 5;          // K-half this lane supplies to MFMA
  const int l31  = lane & 31;
  const int wave = tid >> 6;

  __shared__ float colw[4][1024];      // per-wave col partials (16 KB)

  // --- build A fragments from raw points (row tiles t0, t0+1) ---
  // A k-vec: w0=[hx hy hz hx hy hz lx ly]  w1=[lz 1 1 nh nl 0 0 0]
  const int t0 = rg * 8 + wave * 2;
  bf16x8 af[2];
#pragma unroll
  for (int rr = 0; rr < 2; ++rr) {
    const int r = (t0 + rr) * 32 + l31;
    const float* p = x1 + (size_t)(b * PTS + r) * 3;
    const float x = p[0], y = p[1], zc = p[2];
    const unsigned hx = f2bf(x), hy = f2bf(y), hz = f2bf(zc);
    const unsigned lx = f2bf(x - bf2f(hx));
    const unsigned ly = f2bf(y - bf2f(hy));
    const unsigned lz = f2bf(zc - bf2f(hz));
    const float n = fmaf(x, x, fmaf(y, y, zc * zc));
    const unsigned nh = f2bf(n), nl = f2bf(n - bf2f(nh));
    const unsigned one = 0x3F80u;
    uint4 w0, w1;
    w0.x = pk(hx, hy); w0.y = pk(hz, hx); w0.z = pk(hy, hz); w0.w = pk(lx, ly);
    w1.x = pk(lz, one); w1.y = pk(one, nh); w1.z = pk(nl, 0u); w1.w = 0u;
    uint4 w;
    w.x = half ? w1.x : w0.x; w.y = half ? w1.y : w0.y;
    w.z = half ? w1.z : w0.z; w.w = half ? w1.w : w0.w;
    af[rr] = *(const bf16x8*)&w;
  }
  const bf16x8 af0 = af[0], af1 = af[1];

  f32x16 zero;
#pragma unroll
  for (int e = 0; e < 16; ++e) zero[e] = 0.f;

  float rm0[16], rm1[16];
#pragma unroll
  for (int e = 0; e < 16; ++e) { rm0[e] = 3.0e38f; rm1[e] = 3.0e38f; }

  // --- stream this col-quarter's 32 tiles; explicit double-buffered groups ---
  const uint4* bp = Bfr + ((size_t)(b * TILES + cq * 32) * 2) * 32;
  const int off = half * 32 + l31;  // within a tile: h*32 + col
  bf16x8 bufA[4], bufB[4];
#pragma unroll
  for (int t = 0; t < 4; ++t) bufA[t] = *(const bf16x8*)&bp[t * 64 + off];

  GBODY(0, bufA, bufB);
  GBODY(1, bufB, bufA);
  GBODY(2, bufA, bufB);
  GBODY(3, bufB, bufA);
  GBODY(4, bufA, bufB);
  GBODY(5, bufB, bufA);
  GBODY(6, bufA, bufB);
  GBODY(7, bufB, bufA);  // final prefetch wraps to tiles 0-3: redundant, safe

  // --- per-row min over this wave's 32 cols, direct store (no atomics) ---
  // C/D layout: col = lane&31, row_local = (e&3) + 8*(e>>2) + 4*half.
  float* rb = rowpart + (size_t)(b * 4 + cq) * PTS + t0 * 32;
#pragma unroll
  for (int e = 0; e < 16; ++e) {
    float v = rm0[e];
    v = fminf(v, __shfl_xor(v, 1));
    v = fminf(v, __shfl_xor(v, 2));
    v = fminf(v, __shfl_xor(v, 4));
    v = fminf(v, __shfl_xor(v, 8));
    v = fminf(v, __shfl_xor(v, 16));
    if (l31 == e) rb[(e & 3) + 8 * (e >> 2) + 4 * half] = v;
  }
#pragma unroll
  for (int e = 0; e < 16; ++e) {
    float v = rm1[e];
    v = fminf(v, __shfl_xor(v, 1));
    v = fminf(v, __shfl_xor(v, 2));
    v = fminf(v, __shfl_xor(v, 4));
    v = fminf(v, __shfl_xor(v, 8));
    v = fminf(v, __shfl_xor(v, 16));
    if (l31 == e) rb[32 + (e & 3) + 8 * (e >> 2) + 4 * half] = v;
  }

  // --- merge 4 waves' col partials -> colpart[b][rg][col] ---
  __syncthreads();
  float* cb = colpart + (size_t)(b * 16 + rg) * PTS + cq * 1024;
  for (int c = tid; c < 1024; c += 256)
    cb[c] = fminf(fminf(colw[0][c], colw[1][c]),
                  fminf(colw[2][c], colw[3][c]));
}

// ---- reduce: out[b] = (sum_r min_cq rowpart + sum_c min_rg colpart) / PTS ----
// 64 blocks: (b, quarter).  Clamp-to-0 after the min (commutes with fmax).
__global__ __launch_bounds__(256) void reduce_out(
    const float* __restrict__ rowpart, const float* __restrict__ colpart,
    float* __restrict__ out) {
  const int b = blockIdx.x >> 2;
  const int seg = blockIdx.x & 3;
  const int tid = threadIdx.x;
  float s = 0.f;
  const float* rp = rowpart + (size_t)b * 4 * PTS + seg * 1024;
  for (int r = tid; r < 1024; r += 256) {
    float m = fminf(fminf(rp[r], rp[PTS + r]),
                    fminf(rp[2 * PTS + r], rp[3 * PTS + r]));
    s += fmaxf(m, 0.f);
  }
  const float* cp = colpart + (size_t)b * 16 * PTS + seg * 1024;
  for (int c = tid; c < 1024; c += 256) {
    float m = cp[c];
#pragma unroll
    for (int k = 1; k < 16; ++k) m = fminf(m, cp[(size_t)k * PTS + c]);
    s += fmaxf(m, 0.f);
  }
  s += __shfl_xor(s, 1);
  s += __shfl_xor(s, 2);
  s += __shfl_xor(s, 4);
  s += __shfl_xor(s, 8);
  s += __shfl_xor(s, 16);
  s += __shfl_xor(s, 32);
  __shared__ float acc[4];
  if ((tid & 63) == 0) acc[tid >> 6] = s;
  __syncthreads();
  if (tid == 0)
    atomicAdd(&out[b], (acc[0] + acc[1] + acc[2] + acc[3]) * (1.f / PTS));
}

extern "C" void kernel_launch(void* const* d_in, const int* in_sizes, int n_in,
                              void* d_out, int out_size, void* d_ws,
                              size_t ws_size, hipStream_t stream) {
  const float* x1 = (const float*)d_in[0];
  const float* x2 = (const float*)d_in[1];
  float* out = (float*)d_out;

  // ws layout: Bfr 2 MB | rowpart 1 MB | colpart 4 MB
  uint4* Bfr = (uint4*)d_ws;
  float* rowpart = (float*)((char*)d_ws + ((size_t)2 << 20));
  float* colpart = (float*)((char*)d_ws + ((size_t)3 << 20));

  prepack_b<<<(NB * PTS) / 256, 256, 0, stream>>>(x2, Bfr, out);
  dim3 grid(64, NB);  // x = (b,cq) slice -> XCD = x%8 ; y = row-group
  chamfer_main<<<grid, 256, 0, stream>>>(x1, Bfr, rowpart, colpart);
  reduce_out<<<64, 256, 0, stream>>>(rowpart, colpart, out);
}

// Round 4
// 1805.156 us; speedup vs baseline: 1.1371x; 1.1371x over previous
//
#include <hip/hip_runtime.h>

// Chamfer distance, B=16, N=M=4096, D=3.
// dist(i,j) = n1 + n2 - 2*x1.x2 as ONE bf16 MFMA per 32x32 tile (norms folded
// into padded K slots, hi/lo bf16 split => exact-grade).
// R8 (pressure fix): R5-R7 all spilled the PERSISTENT arrays (WRITE ~850 MB
// constant across 3 structures; R7's fences made reload traffic 6.7 GB).
// Lower the demand instead of fighting the allocator:
//  - ONE row-frag per wave (rm 32->16, af 8->4); grid.y 16->32
//  - unpaired tiles: single f32x16 accumulator live (+16 v_min/tile vs min3)
//  - no shfl/branch in loop: both halves write tree16 scalar to per-wave LDS
//  - no sched_barriers (R7 lesson); launch_bounds (256,3)
// Est. live ~104 regs. Fusion halves MFMAs + Bfr stream vs two-pass R4.

typedef __attribute__((ext_vector_type(8))) __bf16 bf16x8;
typedef __attribute__((ext_vector_type(16))) float f32x16;

#define PTS 4096
#define TILES 128  // PTS/32
#define NB 16

__device__ __forceinline__ unsigned f2bf(float f) {
  unsigned u = __float_as_uint(f);
  return (u + 0x7FFFu + ((u >> 16) & 1u)) >> 16;  // RNE bf16 bits
}
__device__ __forceinline__ float bf2f(unsigned s) {
  return __uint_as_float(s << 16);
}
__device__ __forceinline__ unsigned pk(unsigned lo, unsigned hi) {
  return (lo & 0xFFFFu) | (hi << 16);
}
// min over the 16 elements of one accumulator: 7x v_min3 + v_min
__device__ __forceinline__ float tree16(const f32x16 a) {
  const float u0 = fminf(fminf(a[0], a[1]), a[2]);
  const float u1 = fminf(fminf(a[3], a[4]), a[5]);
  const float u2 = fminf(fminf(a[6], a[7]), a[8]);
  const float u3 = fminf(fminf(a[9], a[10]), a[11]);
  const float u4 = fminf(fminf(a[12], a[13]), a[14]);
  const float v0 = fminf(fminf(u0, u1), a[15]);
  const float v1 = fminf(fminf(u2, u3), u4);
  return fminf(v0, v1);
}

// ---- prepack x2-side (column) fragments + zero out ----
// Bfr[((b*TILES+t)*2+h)*32 + l31]
// B k-vec: w0=[Hx Hy Hz Lx Ly Lz Hx Hy]  w1=[Hz nh nl 1 1 0 0 0], H,L split -2q.
__global__ __launch_bounds__(256) void prepack_b(const float* __restrict__ x2,
                                                 uint4* __restrict__ Bfr,
                                                 float* __restrict__ out) {
  const int id = blockIdx.x * 256 + threadIdx.x;  // NB*PTS = 65536
  if (id < NB) out[id] = 0.f;                     // reduce uses atomicAdd
  const int b = id >> 12;
  const int j = id & (PTS - 1);
  const float* q = x2 + (size_t)(b * PTS + j) * 3;
  const float x = q[0], y = q[1], z = q[2];
  const float sx = -2.f * x, sy = -2.f * y, sz = -2.f * z;
  const unsigned Hx = f2bf(sx), Hy = f2bf(sy), Hz = f2bf(sz);
  const unsigned Lx = f2bf(sx - bf2f(Hx));
  const unsigned Ly = f2bf(sy - bf2f(Hy));
  const unsigned Lz = f2bf(sz - bf2f(Hz));
  const float n = fmaf(x, x, fmaf(y, y, z * z));
  const unsigned nh = f2bf(n), nl = f2bf(n - bf2f(nh));
  const unsigned one = 0x3F80u;
  uint4 w0, w1;
  w0.x = pk(Hx, Hy); w0.y = pk(Hz, Lx); w0.z = pk(Ly, Lz); w0.w = pk(Hx, Hy);
  w1.x = pk(Hz, nh); w1.y = pk(nl, one); w1.z = pk(one, 0u); w1.w = 0u;
  uint4* base = Bfr + ((size_t)(b * TILES + (j >> 5)) * 2) * 32 + (j & 31);
  base[0]  = w0;   // half 0 (k 0..7)
  base[32] = w1;   // half 1 (k 8..15)
}

// One tile: single accumulator, consumed immediately (fold + tree + LDS).
#define TSTEP(GT, BREG)                                                       \
  do {                                                                        \
    const f32x16 a =                                                          \
        __builtin_amdgcn_mfma_f32_32x32x16_bf16(af0, BREG, zero, 0, 0, 0);    \
    _Pragma("unroll") for (int e = 0; e < 16; ++e)                            \
        rm[e] = fminf(a[e], rm[e]);                                           \
    cw[(GT)*64] = tree16(a);                                                  \
  } while (0)

// One group of 4 tiles: prefetch next group's 4 into NXT, compute CUR's 4.
#define GBODY(G, CUR, NXT)                                                    \
  do {                                                                        \
    NXT[0] = *(const bf16x8*)&bp[((((G) + 1) & 7) * 4 + 0) * 64 + off];       \
    NXT[1] = *(const bf16x8*)&bp[((((G) + 1) & 7) * 4 + 1) * 64 + off];       \
    NXT[2] = *(const bf16x8*)&bp[((((G) + 1) & 7) * 4 + 2) * 64 + off];       \
    NXT[3] = *(const bf16x8*)&bp[((((G) + 1) & 7) * 4 + 3) * 64 + off];       \
    TSTEP((G)*4 + 0, CUR[0]);                                                 \
    TSTEP((G)*4 + 1, CUR[1]);                                                 \
    TSTEP((G)*4 + 2, CUR[2]);                                                 \
    TSTEP((G)*4 + 3, CUR[3]);                                                 \
  } while (0)

// ---- main: 4 waves, each one row-tile (32 rows); block covers 128 rows.
// All waves share one 32-tile col stream (32 KB, L1/L2-resident).
// grid.x = 64 slices (b,cq) -> XCD = x%8 ; grid.y = 32 row-groups.
__global__ __launch_bounds__(256, 3) void chamfer_main(
    const float* __restrict__ x1, const uint4* __restrict__ Bfr,
    float* __restrict__ rowpart, float* __restrict__ colpart) {
  const int s  = blockIdx.x;           // (b, col-quarter)
  const int b  = s >> 2;
  const int cq = s & 3;
  const int rg = blockIdx.y;           // row-group: 4 row-tiles (128 rows)

  const int tid  = threadIdx.x;
  const int lane = tid & 63;
  const int half = lane >> 5;          // K-half this lane supplies to MFMA
  const int l31  = lane & 31;
  const int wave = tid >> 6;

  __shared__ float colw[4][2048];      // [wave][tile*64 + half*32 + l31] 32 KB

  // --- build the single A fragment (row tile t0) ---
  // A k-vec: w0=[hx hy hz hx hy hz lx ly]  w1=[lz 1 1 nh nl 0 0 0]
  const int t0 = rg * 4 + wave;
  bf16x8 af0;
  {
    const int r = t0 * 32 + l31;
    const float* p = x1 + (size_t)(b * PTS + r) * 3;
    const float x = p[0], y = p[1], zc = p[2];
    const unsigned hx = f2bf(x), hy = f2bf(y), hz = f2bf(zc);
    const unsigned lx = f2bf(x - bf2f(hx));
    const unsigned ly = f2bf(y - bf2f(hy));
    const unsigned lz = f2bf(zc - bf2f(hz));
    const float n = fmaf(x, x, fmaf(y, y, zc * zc));
    const unsigned nh = f2bf(n), nl = f2bf(n - bf2f(nh));
    const unsigned one = 0x3F80u;
    uint4 w0, w1;
    w0.x = pk(hx, hy); w0.y = pk(hz, hx); w0.z = pk(hy, hz); w0.w = pk(lx, ly);
    w1.x = pk(lz, one); w1.y = pk(one, nh); w1.z = pk(nl, 0u); w1.w = 0u;
    uint4 w;
    w.x = half ? w1.x : w0.x; w.y = half ? w1.y : w0.y;
    w.z = half ? w1.z : w0.z; w.w = half ? w1.w : w0.w;
    af0 = *(const bf16x8*)&w;
  }

  f32x16 zero;
#pragma unroll
  for (int e = 0; e < 16; ++e) zero[e] = 0.f;

  float rm[16];
#pragma unroll
  for (int e = 0; e < 16; ++e) rm[e] = 3.0e38f;

  // --- stream this col-quarter's 32 tiles; double-buffered groups of 4 ---
  const uint4* bp = Bfr + ((size_t)(b * TILES + cq * 32) * 2) * 32;
  const int off = half * 32 + l31;        // within a tile: h*32 + col
  float* cw = &colw[wave][half * 32 + l31];
  bf16x8 bufA[4], bufB[4];
#pragma unroll
  for (int t = 0; t < 4; ++t) bufA[t] = *(const bf16x8*)&bp[t * 64 + off];

  GBODY(0, bufA, bufB);
  GBODY(1, bufB, bufA);
  GBODY(2, bufA, bufB);
  GBODY(3, bufB, bufA);
  GBODY(4, bufA, bufB);
  GBODY(5, bufB, bufA);
  GBODY(6, bufA, bufB);
  GBODY(7, bufB, bufA);  // final prefetch wraps to tiles 0-3: redundant, safe

  // --- per-row min over this wave's 32 cols-per-lane, direct store ---
  // C/D layout: col = lane&31, row_local = (e&3) + 8*(e>>2) + 4*half.
  float* rb = rowpart + (size_t)(b * 4 + cq) * PTS + t0 * 32;
#pragma unroll
  for (int e = 0; e < 16; ++e) {
    float v = rm[e];
    v = fminf(v, __shfl_xor(v, 1));
    v = fminf(v, __shfl_xor(v, 2));
    v = fminf(v, __shfl_xor(v, 4));
    v = fminf(v, __shfl_xor(v, 8));
    v = fminf(v, __shfl_xor(v, 16));
    if (l31 == e) rb[(e & 3) + 8 * (e >> 2) + 4 * half] = v;
  }

  // --- merge 4 waves x 2 halves of col partials -> colpart[b][rg][col] ---
  __syncthreads();
  float* cb = colpart + (size_t)(b * 32 + rg) * PTS + cq * 1024;
  for (int c = tid; c < 1024; c += 256) {
    const int base = (c >> 5) * 64 + (c & 31);
    float m = colw[0][base];
    m = fminf(m, colw[0][base + 32]);
    m = fminf(m, fminf(colw[1][base], colw[1][base + 32]));
    m = fminf(m, fminf(colw[2][base], colw[2][base + 32]));
    m = fminf(m, fminf(colw[3][base], colw[3][base + 32]));
    cb[c] = m;
  }
}

// ---- reduce: out[b] = (sum_r min_cq rowpart + sum_c min_rg colpart) / PTS ----
// 64 blocks: (b, quarter).  Clamp-to-0 after the min (commutes with fmax).
__global__ __launch_bounds__(256) void reduce_out(
    const float* __restrict__ rowpart, const float* __restrict__ colpart,
    float* __restrict__ out) {
  const int b = blockIdx.x >> 2;
  const int seg = blockIdx.x & 3;
  const int tid = threadIdx.x;
  float s = 0.f;
  const float* rp = rowpart + (size_t)b * 4 * PTS + seg * 1024;
  for (int r = tid; r < 1024; r += 256) {
    float m = fminf(fminf(rp[r], rp[PTS + r]),
                    fminf(rp[2 * PTS + r], rp[3 * PTS + r]));
    s += fmaxf(m, 0.f);
  }
  const float* cp = colpart + (size_t)b * 32 * PTS + seg * 1024;
  for (int c = tid; c < 1024; c += 256) {
    float m = cp[c];
#pragma unroll
    for (int k = 1; k < 32; ++k) m = fminf(m, cp[(size_t)k * PTS + c]);
    s += fmaxf(m, 0.f);
  }
  s += __shfl_xor(s, 1);
  s += __shfl_xor(s, 2);
  s += __shfl_xor(s, 4);
  s += __shfl_xor(s, 8);
  s += __shfl_xor(s, 16);
  s += __shfl_xor(s, 32);
  __shared__ float acc[4];
  if ((tid & 63) == 0) acc[tid >> 6] = s;
  __syncthreads();
  if (tid == 0)
    atomicAdd(&out[b], (acc[0] + acc[1] + acc[2] + acc[3]) * (1.f / PTS));
}

extern "C" void kernel_launch(void* const* d_in, const int* in_sizes, int n_in,
                              void* d_out, int out_size, void* d_ws,
                              size_t ws_size, hipStream_t stream) {
  const float* x1 = (const float*)d_in[0];
  const float* x2 = (const float*)d_in[1];
  float* out = (float*)d_out;

  // ws layout: Bfr 2 MB | rowpart 1 MB | colpart 8 MB
  uint4* Bfr = (uint4*)d_ws;
  float* rowpart = (float*)((char*)d_ws + ((size_t)2 << 20));
  float* colpart = (float*)((char*)d_ws + ((size_t)3 << 20));

  prepack_b<<<(NB * PTS) / 256, 256, 0, stream>>>(x2, Bfr, out);
  dim3 grid(64, 32);  // x = (b,cq) slice -> XCD = x%8 ; y = row-group
  chamfer_main<<<grid, 256, 0, stream>>>(x1, Bfr, rowpart, colpart);
  reduce_out<<<64, 256, 0, stream>>>(rowpart, colpart, out);
}

// Round 5
// 85.648 us; speedup vs baseline: 23.9657x; 21.0765x over previous
//
#include <hip/hip_runtime.h>

// Chamfer distance, B=16, N=M=4096, D=3.
// dist(i,j) = n1 + n2 - 2*x1.x2 as ONE bf16 MFMA per 32x32 tile (norms folded
// into padded K slots, hi/lo bf16 split => exact-grade; absmax 0.0 since R1).
// R9: REVERT to the verified R4 two-pass kernel. R5-R8's fused row+col design
// spilled unconditionally (~850 MB scratch writes even at VGPR cap 256) —
// the dual consumption of each MFMA accumulator (row fold + col tree) makes
// the backend demote the fold arrays to scratch regardless of pressure.
// Two-pass (d=0: rows=x1, d=1: rows=x2) keeps ONE consumer per accumulator.
// Only change vs R4: reduce_rows widened 16 -> 64 blocks (atomicAdd; out
// zeroed in prepack) — does not touch chamfer_main codegen.

typedef __attribute__((ext_vector_type(8))) __bf16 bf16x8;
typedef __attribute__((ext_vector_type(16))) float f32x16;

#define PTS 4096
#define TILES 128  // PTS/32
#define NB 16

__device__ __forceinline__ unsigned f2bf(float f) {
  unsigned u = __float_as_uint(f);
  return (u + 0x7FFFu + ((u >> 16) & 1u)) >> 16;  // RNE bf16 bits
}
__device__ __forceinline__ float bf2f(unsigned s) {
  return __uint_as_float(s << 16);
}
__device__ __forceinline__ unsigned pk(unsigned lo, unsigned hi) {
  return (lo & 0xFFFFu) | (hi << 16);
}

// ---- prepack B-side fragments + init rowm + zero out ----
// Bfr[(((d*NB+b)*TILES+t)*2+h)*32 + l31]
// B k-vec: w0=[Hx Hy Hz Lx Ly Lz Hx Hy]  w1=[Hz nh nl 1 1 0 0 0], H,L split -2q.
__global__ __launch_bounds__(256) void prepack_b(const float* __restrict__ x1,
                                                 const float* __restrict__ x2,
                                                 uint4* __restrict__ Bfr,
                                                 unsigned* __restrict__ rowm,
                                                 float* __restrict__ out) {
  const int id = blockIdx.x * 256 + threadIdx.x;  // 2*NB*PTS = 131072
  rowm[id] = 0x7F800000u;                         // +inf (all dists >= 0)
  if (id < NB) out[id] = 0.f;                     // reduce uses atomicAdd
  const int d = id >> 16;
  const int b = (id >> 12) & (NB - 1);
  const int j = id & (PTS - 1);
  const float* q = (d ? x1 : x2) + (size_t)(b * PTS + j) * 3;
  const float x = q[0], y = q[1], z = q[2];
  const float sx = -2.f * x, sy = -2.f * y, sz = -2.f * z;
  const unsigned Hx = f2bf(sx), Hy = f2bf(sy), Hz = f2bf(sz);
  const unsigned Lx = f2bf(sx - bf2f(Hx));
  const unsigned Ly = f2bf(sy - bf2f(Hy));
  const unsigned Lz = f2bf(sz - bf2f(Hz));
  const float n = fmaf(x, x, fmaf(y, y, z * z));
  const unsigned nh = f2bf(n), nl = f2bf(n - bf2f(nh));
  const unsigned one = 0x3F80u;
  uint4 w0, w1;
  w0.x = pk(Hx, Hy); w0.y = pk(Hz, Lx); w0.z = pk(Ly, Lz); w0.w = pk(Hx, Hy);
  w1.x = pk(Hz, nh); w1.y = pk(nl, one); w1.z = pk(one, 0u); w1.w = 0u;
  uint4* base =
      Bfr + ((size_t)((d * NB + b) * TILES + (j >> 5)) * 2) * 32 + (j & 31);
  base[0]  = w0;   // half 0
  base[32] = w1;   // half 1
}

// ---- main: 256 threads (4 waves). All 4 waves stream the SAME 64 col-tiles
// (different rows) -> L1 temporal reuse. No LDS, no barriers.
__global__ __launch_bounds__(256, 4) void chamfer_main(
    const float* __restrict__ x1, const float* __restrict__ x2,
    const uint4* __restrict__ Bfr, unsigned* __restrict__ rowm) {
  const int s  = blockIdx.x;           // 64 slices: (dir, batch, colhalf)
  const int d  = s & 1;
  const int b  = (s >> 1) & (NB - 1);
  const int ch = (s >> 5) & 1;
  const int rg = blockIdx.y;           // 16 row-groups of 256 rows

  const int tid  = threadIdx.x;
  const int lane = tid & 63;
  const int half = lane >> 5;          // K-half this lane supplies to MFMA
  const int l31  = lane & 31;
  const int wave = tid >> 6;

  // --- build A fragments from raw points (row tiles t0, t0+1) ---
  // A k-vec: w0=[hx hy hz hx hy hz lx ly]  w1=[lz 1 1 nh nl 0 0 0]
  const float* P = d ? x2 : x1;
  const int t0 = rg * 8 + wave * 2;
  bf16x8 af[2];
#pragma unroll
  for (int rr = 0; rr < 2; ++rr) {
    const int r = (t0 + rr) * 32 + l31;
    const float* p = P + (size_t)(b * PTS + r) * 3;
    const float x = p[0], y = p[1], zc = p[2];
    const unsigned hx = f2bf(x), hy = f2bf(y), hz = f2bf(zc);
    const unsigned lx = f2bf(x - bf2f(hx));
    const unsigned ly = f2bf(y - bf2f(hy));
    const unsigned lz = f2bf(zc - bf2f(hz));
    const float n = fmaf(x, x, fmaf(y, y, zc * zc));
    const unsigned nh = f2bf(n), nl = f2bf(n - bf2f(nh));
    const unsigned one = 0x3F80u;
    uint4 w0, w1;
    w0.x = pk(hx, hy); w0.y = pk(hz, hx); w0.z = pk(hy, hz); w0.w = pk(lx, ly);
    w1.x = pk(lz, one); w1.y = pk(one, nh); w1.z = pk(nl, 0u); w1.w = 0u;
    uint4 w;
    w.x = half ? w1.x : w0.x; w.y = half ? w1.y : w0.y;
    w.z = half ? w1.z : w0.z; w.w = half ? w1.w : w0.w;
    af[rr] = *(const bf16x8*)&w;
  }
  const bf16x8 af0 = af[0], af1 = af[1];

  f32x16 zero;
#pragma unroll
  for (int e = 0; e < 16; ++e) zero[e] = 0.f;

  float rm0[16], rm1[16];
#pragma unroll
  for (int e = 0; e < 16; ++e) { rm0[e] = 3.0e38f; rm1[e] = 3.0e38f; }

  // --- stream this col-half's 64 tiles; 8-slot ring, 4 loads in flight ---
  const uint4* bp = Bfr + ((size_t)((d * NB + b) * TILES + ch * 64) * 2) * 32;
  const int off = half * 32 + l31;  // within a tile: h*32 + col
  bf16x8 buf[8];
#pragma unroll
  for (int t = 0; t < 4; ++t) buf[t] = *(const bf16x8*)&bp[t * 64 + off];

#pragma unroll 2
  for (int g = 0; g < 16; ++g) {
    const int cur = (g & 1) * 4;
    const int nxt = ((g + 1) & 1) * 4;
    const int pf  = ((g + 1) & 15) * 4;  // wrap: last prefetch redundant, safe
#pragma unroll
    for (int t = 0; t < 4; ++t)
      buf[nxt + t] = *(const bf16x8*)&bp[(pf + t) * 64 + off];
#pragma unroll
    for (int t = 0; t < 4; t += 2) {
      const bf16x8 b0 = buf[cur + t], b1 = buf[cur + t + 1];
      const f32x16 a00 =
          __builtin_amdgcn_mfma_f32_32x32x16_bf16(af0, b0, zero, 0, 0, 0);
      const f32x16 a01 =
          __builtin_amdgcn_mfma_f32_32x32x16_bf16(af0, b1, zero, 0, 0, 0);
#pragma unroll
      for (int e = 0; e < 16; ++e)
        rm0[e] = fminf(fminf(a00[e], a01[e]), rm0[e]);  // v_min3_f32
      const f32x16 a10 =
          __builtin_amdgcn_mfma_f32_32x32x16_bf16(af1, b0, zero, 0, 0, 0);
      const f32x16 a11 =
          __builtin_amdgcn_mfma_f32_32x32x16_bf16(af1, b1, zero, 0, 0, 0);
#pragma unroll
      for (int e = 0; e < 16; ++e)
        rm1[e] = fminf(fminf(a10[e], a11[e]), rm1[e]);
    }
  }

  // --- per-row min over this wave's 32 cols-per-half, then uint atomicMin ---
  // C/D layout: col = lane&31, row_local = (e&3) + 8*(e>>2) + 4*half.
  unsigned* rbase = rowm + (size_t)(d * NB + b) * PTS + t0 * 32;
#pragma unroll
  for (int e = 0; e < 16; ++e) {
    float v = rm0[e];
    v = fminf(v, __shfl_xor(v, 1));
    v = fminf(v, __shfl_xor(v, 2));
    v = fminf(v, __shfl_xor(v, 4));
    v = fminf(v, __shfl_xor(v, 8));
    v = fminf(v, __shfl_xor(v, 16));
    if (l31 == e) {
      const int rl = (e & 3) + 8 * (e >> 2) + 4 * half;
      atomicMin(rbase + rl, __float_as_uint(fmaxf(v, 0.f)));
    }
  }
#pragma unroll
  for (int e = 0; e < 16; ++e) {
    float v = rm1[e];
    v = fminf(v, __shfl_xor(v, 1));
    v = fminf(v, __shfl_xor(v, 2));
    v = fminf(v, __shfl_xor(v, 4));
    v = fminf(v, __shfl_xor(v, 8));
    v = fminf(v, __shfl_xor(v, 16));
    if (l31 == e) {
      const int rl = 32 + (e & 3) + 8 * (e >> 2) + 4 * half;
      atomicMin(rbase + rl, __float_as_uint(fmaxf(v, 0.f)));
    }
  }
}

// ---- reduce: out[b] += partial sums of rowmin; 64 blocks (b, quarter) ----
__global__ __launch_bounds__(256) void reduce_rows(
    const unsigned* __restrict__ rowm, float* __restrict__ out) {
  const int b = blockIdx.x >> 2;
  const int seg = blockIdx.x & 3;
  const int tid = threadIdx.x;
  const unsigned* r0 = rowm + (size_t)b * PTS + seg * 1024;
  const unsigned* r1 = rowm + (size_t)(NB + b) * PTS + seg * 1024;
  float s = 0.f;
  for (int i = tid; i < 1024; i += 256)
    s += __uint_as_float(r0[i]) + __uint_as_float(r1[i]);
  s += __shfl_xor(s, 1);
  s += __shfl_xor(s, 2);
  s += __shfl_xor(s, 4);
  s += __shfl_xor(s, 8);
  s += __shfl_xor(s, 16);
  s += __shfl_xor(s, 32);
  __shared__ float acc[4];
  if ((tid & 63) == 0) acc[tid >> 6] = s;
  __syncthreads();
  if (tid == 0)
    atomicAdd(&out[b], (acc[0] + acc[1] + acc[2] + acc[3]) * (1.f / PTS));
}

extern "C" void kernel_launch(void* const* d_in, const int* in_sizes, int n_in,
                              void* d_out, int out_size, void* d_ws,
                              size_t ws_size, hipStream_t stream) {
  const float* x1 = (const float*)d_in[0];
  const float* x2 = (const float*)d_in[1];
  float* out = (float*)d_out;

  uint4* Bfr = (uint4*)d_ws;  // 2*NB*TILES*2*32 uint4 = 4 MB
  unsigned* rowm =
      (unsigned*)((char*)d_ws + (size_t)2 * NB * TILES * 2 * 32 * 16);

  prepack_b<<<(2 * NB * PTS) / 256, 256, 0, stream>>>(x1, x2, Bfr, rowm, out);
  dim3 grid(64, NB);  // x = (dir,b,ch) slice -> XCD = x%8 ; y = row-group
  chamfer_main<<<grid, 256, 0, stream>>>(x1, x2, Bfr, rowm);
  reduce_rows<<<64, 256, 0, stream>>>(rowm, out);
}

// Round 6
// 84.973 us; speedup vs baseline: 24.1560x; 1.0079x over previous
//
#include <hip/hip_runtime.h>

// Chamfer distance, B=16, N=M=4096, D=3.
// dist(i,j) = n1 + n2 - 2*x1.x2 as ONE bf16 MFMA per 32x32 tile (norms folded
// into padded K slots, hi/lo bf16 split => exact-grade; absmax 0.0 since R1).
// R10: ring 8 -> 4 slots (groups of 2 tiles, 32 g-iters). Theory: R9 main's
// live set (~130 VGPR: rm 32 + ring 32 + zero 16 + af 8 + 2 accs 32 + addr)
// sits JUST over the 128 cap of launch_bounds(256,4) -> hidden scratch RMW
// per tile (main never appears in top-5; fills mask it). Freeing 16 regs
// (ring 32->16) brings live ~114 < 128 at unchanged 4 waves/SIMD occupancy.
// Prefetch distance 2 tiles still covers L2 latency (~200cyc < ~600cyc of
// per-group wall time across 4 waves). Inner pair-step codegen unchanged
// (2 MFMA -> fold -> 2 MFMA -> fold; the proven no-spill shape).
// Two-pass (d=0: rows=x1, d=1: rows=x2); R5-R8's fused one-pass abandoned
// (dual-consumer of MFMA acc spills unconditionally, see R8 post-mortem).

typedef __attribute__((ext_vector_type(8))) __bf16 bf16x8;
typedef __attribute__((ext_vector_type(16))) float f32x16;

#define PTS 4096
#define TILES 128  // PTS/32
#define NB 16

__device__ __forceinline__ unsigned f2bf(float f) {
  unsigned u = __float_as_uint(f);
  return (u + 0x7FFFu + ((u >> 16) & 1u)) >> 16;  // RNE bf16 bits
}
__device__ __forceinline__ float bf2f(unsigned s) {
  return __uint_as_float(s << 16);
}
__device__ __forceinline__ unsigned pk(unsigned lo, unsigned hi) {
  return (lo & 0xFFFFu) | (hi << 16);
}

// ---- prepack B-side fragments + init rowm + zero out ----
// Bfr[(((d*NB+b)*TILES+t)*2+h)*32 + l31]
// B k-vec: w0=[Hx Hy Hz Lx Ly Lz Hx Hy]  w1=[Hz nh nl 1 1 0 0 0], H,L split -2q.
__global__ __launch_bounds__(256) void prepack_b(const float* __restrict__ x1,
                                                 const float* __restrict__ x2,
                                                 uint4* __restrict__ Bfr,
                                                 unsigned* __restrict__ rowm,
                                                 float* __restrict__ out) {
  const int id = blockIdx.x * 256 + threadIdx.x;  // 2*NB*PTS = 131072
  rowm[id] = 0x7F800000u;                         // +inf (all dists >= 0)
  if (id < NB) out[id] = 0.f;                     // reduce uses atomicAdd
  const int d = id >> 16;
  const int b = (id >> 12) & (NB - 1);
  const int j = id & (PTS - 1);
  const float* q = (d ? x1 : x2) + (size_t)(b * PTS + j) * 3;
  const float x = q[0], y = q[1], z = q[2];
  const float sx = -2.f * x, sy = -2.f * y, sz = -2.f * z;
  const unsigned Hx = f2bf(sx), Hy = f2bf(sy), Hz = f2bf(sz);
  const unsigned Lx = f2bf(sx - bf2f(Hx));
  const unsigned Ly = f2bf(sy - bf2f(Hy));
  const unsigned Lz = f2bf(sz - bf2f(Hz));
  const float n = fmaf(x, x, fmaf(y, y, z * z));
  const unsigned nh = f2bf(n), nl = f2bf(n - bf2f(nh));
  const unsigned one = 0x3F80u;
  uint4 w0, w1;
  w0.x = pk(Hx, Hy); w0.y = pk(Hz, Lx); w0.z = pk(Ly, Lz); w0.w = pk(Hx, Hy);
  w1.x = pk(Hz, nh); w1.y = pk(nl, one); w1.z = pk(one, 0u); w1.w = 0u;
  uint4* base =
      Bfr + ((size_t)((d * NB + b) * TILES + (j >> 5)) * 2) * 32 + (j & 31);
  base[0]  = w0;   // half 0
  base[32] = w1;   // half 1
}

// ---- main: 256 threads (4 waves). All 4 waves stream the SAME 64 col-tiles
// (different rows) -> L1 temporal reuse. No LDS, no barriers.
__global__ __launch_bounds__(256, 4) void chamfer_main(
    const float* __restrict__ x1, const float* __restrict__ x2,
    const uint4* __restrict__ Bfr, unsigned* __restrict__ rowm) {
  const int s  = blockIdx.x;           // 64 slices: (dir, batch, colhalf)
  const int d  = s & 1;
  const int b  = (s >> 1) & (NB - 1);
  const int ch = (s >> 5) & 1;
  const int rg = blockIdx.y;           // 16 row-groups of 256 rows

  const int tid  = threadIdx.x;
  const int lane = tid & 63;
  const int half = lane >> 5;          // K-half this lane supplies to MFMA
  const int l31  = lane & 31;
  const int wave = tid >> 6;

  // --- build A fragments from raw points (row tiles t0, t0+1) ---
  // A k-vec: w0=[hx hy hz hx hy hz lx ly]  w1=[lz 1 1 nh nl 0 0 0]
  const float* P = d ? x2 : x1;
  const int t0 = rg * 8 + wave * 2;
  bf16x8 af[2];
#pragma unroll
  for (int rr = 0; rr < 2; ++rr) {
    const int r = (t0 + rr) * 32 + l31;
    const float* p = P + (size_t)(b * PTS + r) * 3;
    const float x = p[0], y = p[1], zc = p[2];
    const unsigned hx = f2bf(x), hy = f2bf(y), hz = f2bf(zc);
    const unsigned lx = f2bf(x - bf2f(hx));
    const unsigned ly = f2bf(y - bf2f(hy));
    const unsigned lz = f2bf(zc - bf2f(hz));
    const float n = fmaf(x, x, fmaf(y, y, zc * zc));
    const unsigned nh = f2bf(n), nl = f2bf(n - bf2f(nh));
    const unsigned one = 0x3F80u;
    uint4 w0, w1;
    w0.x = pk(hx, hy); w0.y = pk(hz, hx); w0.z = pk(hy, hz); w0.w = pk(lx, ly);
    w1.x = pk(lz, one); w1.y = pk(one, nh); w1.z = pk(nl, 0u); w1.w = 0u;
    uint4 w;
    w.x = half ? w1.x : w0.x; w.y = half ? w1.y : w0.y;
    w.z = half ? w1.z : w0.z; w.w = half ? w1.w : w0.w;
    af[rr] = *(const bf16x8*)&w;
  }
  const bf16x8 af0 = af[0], af1 = af[1];

  f32x16 zero;
#pragma unroll
  for (int e = 0; e < 16; ++e) zero[e] = 0.f;

  float rm0[16], rm1[16];
#pragma unroll
  for (int e = 0; e < 16; ++e) { rm0[e] = 3.0e38f; rm1[e] = 3.0e38f; }

  // --- stream this col-half's 64 tiles; 4-slot ring, 2 loads in flight ---
  const uint4* bp = Bfr + ((size_t)((d * NB + b) * TILES + ch * 64) * 2) * 32;
  const int off = half * 32 + l31;  // within a tile: h*32 + col
  bf16x8 buf[4];
#pragma unroll
  for (int t = 0; t < 2; ++t) buf[t] = *(const bf16x8*)&bp[t * 64 + off];

#pragma unroll 2
  for (int g = 0; g < 32; ++g) {
    const int cur = (g & 1) * 2;
    const int nxt = ((g + 1) & 1) * 2;
    const int pf  = ((g + 1) & 31) * 2;  // wrap: last prefetch redundant, safe
    buf[nxt]     = *(const bf16x8*)&bp[pf * 64 + off];
    buf[nxt + 1] = *(const bf16x8*)&bp[(pf + 1) * 64 + off];
    const bf16x8 b0 = buf[cur], b1 = buf[cur + 1];
    const f32x16 a00 =
        __builtin_amdgcn_mfma_f32_32x32x16_bf16(af0, b0, zero, 0, 0, 0);
    const f32x16 a01 =
        __builtin_amdgcn_mfma_f32_32x32x16_bf16(af0, b1, zero, 0, 0, 0);
#pragma unroll
    for (int e = 0; e < 16; ++e)
      rm0[e] = fminf(fminf(a00[e], a01[e]), rm0[e]);  // v_min3_f32
    const f32x16 a10 =
        __builtin_amdgcn_mfma_f32_32x32x16_bf16(af1, b0, zero, 0, 0, 0);
    const f32x16 a11 =
        __builtin_amdgcn_mfma_f32_32x32x16_bf16(af1, b1, zero, 0, 0, 0);
#pragma unroll
    for (int e = 0; e < 16; ++e)
      rm1[e] = fminf(fminf(a10[e], a11[e]), rm1[e]);
  }

  // --- per-row min over this wave's 32 cols-per-half, then uint atomicMin ---
  // C/D layout: col = lane&31, row_local = (e&3) + 8*(e>>2) + 4*half.
  unsigned* rbase = rowm + (size_t)(d * NB + b) * PTS + t0 * 32;
#pragma unroll
  for (int e = 0; e < 16; ++e) {
    float v = rm0[e];
    v = fminf(v, __shfl_xor(v, 1));
    v = fminf(v, __shfl_xor(v, 2));
    v = fminf(v, __shfl_xor(v, 4));
    v = fminf(v, __shfl_xor(v, 8));
    v = fminf(v, __shfl_xor(v, 16));
    if (l31 == e) {
      const int rl = (e & 3) + 8 * (e >> 2) + 4 * half;
      atomicMin(rbase + rl, __float_as_uint(fmaxf(v, 0.f)));
    }
  }
#pragma unroll
  for (int e = 0; e < 16; ++e) {
    float v = rm1[e];
    v = fminf(v, __shfl_xor(v, 1));
    v = fminf(v, __shfl_xor(v, 2));
    v = fminf(v, __shfl_xor(v, 4));
    v = fminf(v, __shfl_xor(v, 8));
    v = fminf(v, __shfl_xor(v, 16));
    if (l31 == e) {
      const int rl = 32 + (e & 3) + 8 * (e >> 2) + 4 * half;
      atomicMin(rbase + rl, __float_as_uint(fmaxf(v, 0.f)));
    }
  }
}

// ---- reduce: out[b] += partial sums of rowmin; 64 blocks (b, quarter) ----
__global__ __launch_bounds__(256) void reduce_rows(
    const unsigned* __restrict__ rowm, float* __restrict__ out) {
  const int b = blockIdx.x >> 2;
  const int seg = blockIdx.x & 3;
  const int tid = threadIdx.x;
  const unsigned* r0 = rowm + (size_t)b * PTS + seg * 1024;
  const unsigned* r1 = rowm + (size_t)(NB + b) * PTS + seg * 1024;
  float s = 0.f;
  for (int i = tid; i < 1024; i += 256)
    s += __uint_as_float(r0[i]) + __uint_as_float(r1[i]);
  s += __shfl_xor(s, 1);
  s += __shfl_xor(s, 2);
  s += __shfl_xor(s, 4);
  s += __shfl_xor(s, 8);
  s += __shfl_xor(s, 16);
  s += __shfl_xor(s, 32);
  __shared__ float acc[4];
  if ((tid & 63) == 0) acc[tid >> 6] = s;
  __syncthreads();
  if (tid == 0)
    atomicAdd(&out[b], (acc[0] + acc[1] + acc[2] + acc[3]) * (1.f / PTS));
}

extern "C" void kernel_launch(void* const* d_in, const int* in_sizes, int n_in,
                              void* d_out, int out_size, void* d_ws,
                              size_t ws_size, hipStream_t stream) {
  const float* x1 = (const float*)d_in[0];
  const float* x2 = (const float*)d_in[1];
  float* out = (float*)d_out;

  uint4* Bfr = (uint4*)d_ws;  // 2*NB*TILES*2*32 uint4 = 4 MB
  unsigned* rowm =
      (unsigned*)((char*)d_ws + (size_t)2 * NB * TILES * 2 * 32 * 16);

  prepack_b<<<(2 * NB * PTS) / 256, 256, 0, stream>>>(x1, x2, Bfr, rowm, out);
  dim3 grid(64, NB);  // x = (dir,b,ch) slice -> XCD = x%8 ; y = row-group
  chamfer_main<<<grid, 256, 0, stream>>>(x1, x2, Bfr, rowm);
  reduce_rows<<<64, 256, 0, stream>>>(rowm, out);
}